// Round 7
// baseline (3023.661 us; speedup 1.0000x reference)
//
#include <hip/hip_runtime.h>

// Stacked LSTM B=2048,T=512,IN=4,H=64,L=4,OUT=5 — dual-sequence layer pipeline.
// Grid 256 (1 block/CU), block 512 (8 waves; wave-pair (2l,2l+1) = layer l).
// Each block owns TWO groups of 4 batches. Half-iteration i (one barrier each):
//   - pointwise for group g=i&1 using accs produced by iter i-1's MFMA
//   - MFMA for group 1-g (step t̂) — INDEPENDENT of this iteration's pointwise,
//     so the trans chain of one sequence overlaps the MFMA stream of the other
//     (R6's single sequence exposed the full serial chain every step: 5080
//     cyc/iter with only ~2400 busy).
// A 4-batch group needs the same 64 MFMAs/wave as an 8-batch one (M=16 tile),
// so the split is MFMA-issue-neutral. Buffers are 4 rows; A-operand lanes
// ln>=4 read a shared zero page (same-address broadcast -> no bank conflicts).
// Schedule: sigma(l,g,t) = 2(t+l+1)+g = pointwise iter; MFMA at sigma-1.
// Weights: single-plane f16 in registers, prescaled by -log2e (i,f,o) and
// +2log2e (g) so exp2f is direct; bias folded into acc init. Activations
// hi/lo f16 split (2 MFMAs/tile-kt). Extraction: accs live in q=0 lanes
// (rows 0-3); 32 bpermutes + 24 cndmask spread them so all 64 lanes do 2
// h-updates. c-state in registers per (group,rho). FC fused at the end.

#define B_    2048
#define T_    512
#define H_    64
#define OUT_  5
#define RSTR  80            // row stride (f16): 16B-aligned rows, 2-way max banks
#define NITER (2*T_ + 8)
#define LOG2E 1.44269504088896340736f

typedef _Float16 f16;
typedef __attribute__((ext_vector_type(8))) _Float16 f16x8;
typedef __attribute__((ext_vector_type(4))) float f32x4;

__device__ __forceinline__ float rcpf(float v) { return __builtin_amdgcn_rcpf(v); }

__global__ __launch_bounds__(512, 2) void lstm_duo_k(
    const float* __restrict__ x,      // [B,T,4]
    const float* __restrict__ W_ih0,  // [256,4]
    const float* __restrict__ W_ihr,  // [3,256,64]
    const float* __restrict__ W_hh,   // [4,256,64]
    const float* __restrict__ b_ih,   // [4,256]
    const float* __restrict__ b_hh,   // [4,256]
    const float* __restrict__ W_fc,   // [5,64]
    const float* __restrict__ b_fc,   // [5]
    float* __restrict__ out)          // [B,5]
{
    const int tid  = threadIdx.x;
    const int wave = tid >> 6;
    const int l    = wave >> 1;       // layer 0..3
    const int j    = wave & 1;        // half of the layer's units
    const int lane = tid & 63;
    const int q    = lane >> 4;
    const int ln   = lane & 15;
    const int b0   = blockIdx.x * 8;

    // [layer][group][slot][hilo][row 0..3][RSTR]
    __shared__ f16 OWN[4][2][2][2][4][RSTR];   // own-h half (kappa<64)
    __shared__ f16 INB[4][2][2][2][4][RSTR];   // input half (prev-layer h / x)
    __shared__ f16 ZPG[400];                   // zero page for lanes ln>=4
    __shared__ float hf[8][H_ + 1];            // FC staging

    for (int k = tid; k < (int)(sizeof(OWN) / 4); k += 512) ((unsigned*)OWN)[k] = 0u;
    for (int k = tid; k < (int)(sizeof(INB) / 4); k += 512) ((unsigned*)INB)[k] = 0u;
    for (int k = tid; k < (int)(sizeof(ZPG) / 4); k += 512) ((unsigned*)ZPG)[k] = 0u;

    // ---- weights -> f16 B-frags in registers, K phi-permuted, prescaled ----
    // phi(u) = 4*(u&15) + (u>>4); phi^-1(kap) = ((kap&3)<<4) | (kap>>2)
    const float* Whh = W_hh + (size_t)l * 256 * 64;
    const float* Wih = (l == 0) ? W_ih0 : (W_ihr + (size_t)(l - 1) * 256 * 64);
    const float scg[4] = {-LOG2E, -LOG2E, 2.0f * LOG2E, -LOG2E};

    f16x8 Wf[4][2][4];
    float biasv[4][2];
#pragma unroll
    for (int g4 = 0; g4 < 4; ++g4)
#pragma unroll
        for (int s = 0; s < 2; ++s) {
            const int u = (2 * j + s) * 16 + ln;
            const int n = g4 * 64 + u;
            biasv[g4][s] = (b_ih[l * 256 + n] + b_hh[l * 256 + n]) * scg[g4];
#pragma unroll
            for (int kt = 0; kt < 4; ++kt) {
                f16x8 f;
#pragma unroll
                for (int jj = 0; jj < 8; ++jj) {
                    const int kap = kt * 32 + q * 8 + jj;
                    float wv;
                    if (kap < 64) {
                        const int k = ((kap & 3) << 4) | (kap >> 2);
                        wv = Whh[n * 64 + k];
                    } else {
                        const int kk = kap - 64;
                        if (l == 0) wv = (kk < 4) ? Wih[n * 4 + kk] : 0.0f;
                        else { const int k = ((kk & 3) << 4) | (kk >> 2); wv = Wih[n * 64 + k]; }
                    }
                    f[jj] = (f16)(wv * scg[g4]);
                }
                Wf[g4][s][kt] = f;
            }
        }

    // pointwise lane mapping: unit u = (2j+sbar)*16+ln, batches 2*bpar+{0,1}
    const int sbar = q >> 1;
    const int bpar = q & 1;
    const int col4 = 4 * ln + 2 * j + sbar;     // phi(u)
    const int upw  = (2 * j + sbar) * 16 + ln;

    f32x4 acc[4][2];
#pragma unroll
    for (int g4 = 0; g4 < 4; ++g4)
#pragma unroll
        for (int s = 0; s < 2; ++s) acc[g4][s] = (f32x4){0.f, 0.f, 0.f, 0.f};
    float cst[2][2] = {{0.f, 0.f}, {0.f, 0.f}};  // [group][rho]

    // ---- x pipeline (wave 0, lanes 0..15) ----
    const int xb = ln >> 2, xe = ln & 3;
    float xcur[2] = {0.f, 0.f}, xnxt[2] = {0.f, 0.f};
    if (wave == 0 && lane < 16) {
#pragma unroll
        for (int g = 0; g < 2; ++g) {
            xcur[g] = x[(size_t)(b0 + 4 * g + xb) * (T_ * 4) + xe];
            xnxt[g] = x[(size_t)(b0 + 4 * g + xb) * (T_ * 4) + 4 + xe];
        }
    }

    auto half_iter = [&](int i, int g) {
        __syncthreads();
        const int gh = g ^ 1;                        // MFMA group
        const int th = ((i + g) >> 1) - 1 - l;       // MFMA timestep
        const int tp = ((i - g) >> 1) - 1 - l;       // pointwise timestep

        // ---- x stage (step tx, consumed next iter) + prefetch (early issue) ----
        if (wave == 0 && lane < 16) {
            const int tx = (i - g) >> 1;
            if (tx < T_) {
                const f16 hh = (f16)xcur[g];
                const f16 hl = (f16)(xcur[g] - (float)hh);
                f16* dst = &INB[0][g][tx & 1][0][xb][xe];
                dst[0] = hh;
                dst[4 * RSTR] = hl;
            }
            xcur[g] = xnxt[g];
            if (tx + 2 < T_)
                xnxt[g] = x[(size_t)(b0 + 4 * g + xb) * (T_ * 4) + (tx + 2) * 4 + xe];
        }

        // ---- extraction: accs of iter i-1 (group g, step tp) -> 2 updates/lane ----
        float vals[4][2];
#pragma unroll
        for (int g4 = 0; g4 < 4; ++g4) {
            float bc[2][4];
#pragma unroll
            for (int s = 0; s < 2; ++s)
#pragma unroll
                for (int b = 0; b < 4; ++b)
                    bc[s][b] = __shfl(acc[g4][s][b], ln, 64);   // from q=0 lane ln
#pragma unroll
            for (int r = 0; r < 2; ++r) {
                const float a0 = bpar ? bc[0][2 + r] : bc[0][r];
                const float a1 = bpar ? bc[1][2 + r] : bc[1][r];
                vals[g4][r] = sbar ? a1 : a0;
            }
        }

        // ---- MFMA for (gh, th): overlaps the pointwise below (independent) ----
        if (th >= 0 && th < T_) {
            const int ph = th & 1;
            const f16* ownB = (ln < 4) ? &OWN[l][gh][ph][0][ln][0] : &ZPG[0];
            const f16* inB  = (ln < 4) ? &INB[l][gh][ph][0][ln][0] : &ZPG[0];
            const f16x8 A0h = *(const f16x8*)(ownB + q * 8);
            const f16x8 A1h = *(const f16x8*)(ownB + 32 + q * 8);
            const f16x8 A0l = *(const f16x8*)(ownB + 4 * RSTR + q * 8);
            const f16x8 A1l = *(const f16x8*)(ownB + 4 * RSTR + 32 + q * 8);
            const f16x8 A2h = *(const f16x8*)(inB + q * 8);
            const f16x8 A3h = *(const f16x8*)(inB + 32 + q * 8);
            const f16x8 A2l = *(const f16x8*)(inB + 4 * RSTR + q * 8);
            const f16x8 A3l = *(const f16x8*)(inB + 4 * RSTR + 32 + q * 8);
#pragma unroll
            for (int g4 = 0; g4 < 4; ++g4)
#pragma unroll
                for (int s = 0; s < 2; ++s)
                    acc[g4][s] = (f32x4){biasv[g4][s], biasv[g4][s], biasv[g4][s], biasv[g4][s]};
#pragma unroll
            for (int g4 = 0; g4 < 4; ++g4)
#pragma unroll
                for (int s = 0; s < 2; ++s) {
                    acc[g4][s] = __builtin_amdgcn_mfma_f32_16x16x32_f16(A0h, Wf[g4][s][0], acc[g4][s], 0, 0, 0);
                    acc[g4][s] = __builtin_amdgcn_mfma_f32_16x16x32_f16(A0l, Wf[g4][s][0], acc[g4][s], 0, 0, 0);
                    acc[g4][s] = __builtin_amdgcn_mfma_f32_16x16x32_f16(A1h, Wf[g4][s][1], acc[g4][s], 0, 0, 0);
                    acc[g4][s] = __builtin_amdgcn_mfma_f32_16x16x32_f16(A1l, Wf[g4][s][1], acc[g4][s], 0, 0, 0);
                    acc[g4][s] = __builtin_amdgcn_mfma_f32_16x16x32_f16(A2h, Wf[g4][s][2], acc[g4][s], 0, 0, 0);
                    acc[g4][s] = __builtin_amdgcn_mfma_f32_16x16x32_f16(A2l, Wf[g4][s][2], acc[g4][s], 0, 0, 0);
                    acc[g4][s] = __builtin_amdgcn_mfma_f32_16x16x32_f16(A3h, Wf[g4][s][3], acc[g4][s], 0, 0, 0);
                    acc[g4][s] = __builtin_amdgcn_mfma_f32_16x16x32_f16(A3l, Wf[g4][s][3], acc[g4][s], 0, 0, 0);
                }
        }

        // ---- pointwise for (g, tp) ----
        if (tp >= 0 && tp < T_) {
            const int wsO = (tp + 1) & 1, wsI = tp & 1;
            f16* ownW = &OWN[l][g][wsO][0][2 * bpar][col4];
            f16* inW  = (l < 3) ? &INB[l + 1][g][wsI][0][2 * bpar][col4] : (f16*)&ZPG[0];
#pragma unroll
            for (int r = 0; r < 2; ++r) {
                const float si = rcpf(1.0f + exp2f(vals[0][r]));          // pre-scaled -log2e
                const float sf = rcpf(1.0f + exp2f(vals[1][r]));
                const float tg = 1.0f - 2.0f * rcpf(1.0f + exp2f(vals[2][r]));  // +2log2e
                const float so = rcpf(1.0f + exp2f(vals[3][r]));
                const float c  = sf * cst[g][r] + si * tg;
                cst[g][r] = c;
                const float tc = 1.0f - 2.0f * rcpf(1.0f + exp2f(c * (2.0f * LOG2E)));
                const float h  = so * tc;
                const f16 hh = (f16)h;
                const f16 hl = (f16)(h - (float)hh);
                ownW[r * RSTR] = hh;
                ownW[r * RSTR + 4 * RSTR] = hl;
                if (l < 3) { inW[r * RSTR] = hh; inW[r * RSTR + 4 * RSTR] = hl; }
                if (l == 3 && tp == T_ - 1) hf[4 * g + 2 * bpar + r][upw] = h;
            }
        }
    };

#pragma unroll 1
    for (int i = 0; i < NITER; i += 2) {
        half_iter(i, 0);        // g known at compile time -> cst/xcur fold to regs
        half_iter(i + 1, 1);
    }

    // ---- FC on h(T-1) of layer 3 ----
    __syncthreads();
    if (tid < 8 * OUT_) {
        const int b = tid / OUT_, o = tid % OUT_;
        float a = b_fc[o];
#pragma unroll
        for (int k = 0; k < H_; ++k)
            a = fmaf(hf[b][k], W_fc[o * H_ + k], a);
        out[(b0 + b) * OUT_ + o] = a;
    }
}

extern "C" void kernel_launch(void* const* d_in, const int* in_sizes, int n_in,
                              void* d_out, int out_size, void* d_ws, size_t ws_size,
                              hipStream_t stream) {
    const float* x     = (const float*)d_in[0];
    const float* W_ih0 = (const float*)d_in[1];
    const float* W_ihr = (const float*)d_in[2];
    const float* W_hh  = (const float*)d_in[3];
    const float* b_ih  = (const float*)d_in[4];
    const float* b_hh  = (const float*)d_in[5];
    const float* W_fc  = (const float*)d_in[6];
    const float* b_fc  = (const float*)d_in[7];
    float* out = (float*)d_out;

    lstm_duo_k<<<dim3(B_ / 8), dim3(512), 0, stream>>>(
        x, W_ih0, W_ihr, W_hh, b_ih, b_hh, W_fc, b_fc, out);
}

// Round 8
// 1268.121 us; speedup vs baseline: 2.3844x; 2.3844x over previous
//
#include <hip/hip_runtime.h>

// Stacked LSTM B=2048,T=512,IN=4,H=64,L=4,OUT=5 — R6 structure, instruction diet.
// Grid 256 (all CUs), block 512 (8 waves; wave-pair (2l,2l+1) = layer l), NB=8
// batches/block, layers skewed by 1 step in one block, h via double-buffered
// LDS, ONE __syncthreads/iter, T+3=515 iterations. (R7's dual-4-batch split
// DOUBLED MFMA work + barriers -> 3024us; reverted.)
// Diet vs R6 (target: ~600 VALU instr/wave/iter measured -> ~450):
//  - Row-spread staging: batch b -> A-row rho(b)=4*(b>>1)+(b&1). Valid D rows
//    = 4q+{0,1}, so every lane owns its 4 h-updates locally in acc regs:
//    NO shfl/bpermute redistribution (removes 32 ops + an LDS hop from chain).
//  - Weights/bias prescaled by -log2e (i,f,o) / +2log2e (g): direct exp2f
//    (validated R7: identical absmax).
//  - acc initialized to bias (saves 16 adds).
//  - h staged as f16x2 pairs (s=0,1 adjacent cols): 8 ds_write_b32 vs 16 b16.
//  - RSTR=136 (272B row stride): clean 2-way LDS banking (free).
// Math: 16x16x32 f16 MFMA, single-plane f16 weights in regs, hi/lo f16 split
// activations (2 MFMAs per K-tile). FC fused at end.

#define B_    2048
#define T_    512
#define H_    64
#define OUT_  5
#define RSTR  136
#define LOG2E 1.44269504088896340736f

typedef _Float16 f16;
typedef __attribute__((ext_vector_type(8))) _Float16 f16x8;
typedef __attribute__((ext_vector_type(2))) _Float16 f16x2;
typedef __attribute__((ext_vector_type(4))) float f32x4;

__device__ __forceinline__ float rcpf(float v) { return __builtin_amdgcn_rcpf(v); }

__global__ __launch_bounds__(512, 2) void lstm_diet_k(
    const float* __restrict__ x,      // [B,T,4]
    const float* __restrict__ W_ih0,  // [256,4]
    const float* __restrict__ W_ihr,  // [3,256,64]
    const float* __restrict__ W_hh,   // [4,256,64]
    const float* __restrict__ b_ih,   // [4,256]
    const float* __restrict__ b_hh,   // [4,256]
    const float* __restrict__ W_fc,   // [5,64]
    const float* __restrict__ b_fc,   // [5]
    float* __restrict__ out)          // [B,5]
{
    const int tid  = threadIdx.x;
    const int wave = tid >> 6;
    const int l    = wave >> 1;       // layer 0..3
    const int j    = wave & 1;        // half of the layer's units
    const int lane = tid & 63;
    const int q    = lane >> 4;
    const int ln   = lane & 15;
    const int b0   = blockIdx.x * 8;

    // [layer][parity][hilo][row 0..15][RSTR]; cols 0..63 own-h (phi-permuted),
    // 64..127 input (prev-layer h phi-permuted, or x for layer 0). 69.6 KB.
    __shared__ f16 buf[4][2][2][16][RSTR];
    __shared__ float hf[8][H_ + 1];   // FC staging

    for (int k = tid; k < (int)(sizeof(buf) / 4); k += 512) ((unsigned*)buf)[k] = 0u;

    // ---- weights -> f16 B-frags in registers, K phi-permuted, prescaled ----
    // phi(u) = 4*(u&15) + (u>>4); phi^-1(kap) = ((kap&3)<<4) | (kap>>2)
    const float* Whh = W_hh + (size_t)l * 256 * 64;
    const float* Wih = (l == 0) ? W_ih0 : (W_ihr + (size_t)(l - 1) * 256 * 64);
    const float scg[4] = {-LOG2E, -LOG2E, 2.0f * LOG2E, -LOG2E};

    f16x8 Wf[4][2][4];                // [gate][s][kt]
    float biasv[4][2];
#pragma unroll
    for (int g4 = 0; g4 < 4; ++g4)
#pragma unroll
        for (int s = 0; s < 2; ++s) {
            const int u = (2 * j + s) * 16 + ln;
            const int n = g4 * 64 + u;
            biasv[g4][s] = (b_ih[l * 256 + n] + b_hh[l * 256 + n]) * scg[g4];
#pragma unroll
            for (int kt = 0; kt < 4; ++kt) {
                f16x8 f;
#pragma unroll
                for (int jj = 0; jj < 8; ++jj) {
                    const int kap = kt * 32 + q * 8 + jj;
                    float wv;
                    if (kap < 64) {
                        const int k = ((kap & 3) << 4) | (kap >> 2);
                        wv = Whh[n * 64 + k];
                    } else {
                        const int kk = kap - 64;
                        if (l == 0) wv = (kk < 4) ? Wih[n * 4 + kk] : 0.0f;
                        else { const int k = ((kk & 3) << 4) | (kk >> 2); wv = Wih[n * 64 + k]; }
                    }
                    f[jj] = (f16)(wv * scg[g4]);
                }
                Wf[g4][s][kt] = f;
            }
        }

    // parity-indexed base pointers (single select per iteration)
    const f16* rdB[2] = {&buf[l][0][0][0][0], &buf[l][1][0][0][0]};
    f16* wrO[2] = {&buf[l][0][0][0][0], &buf[l][1][0][0][0]};
    const int ln1 = (l < 3) ? l + 1 : 3;
    f16* wrI[2] = {&buf[ln1][0][0][0][0], &buf[ln1][1][0][0][0]};

    // per-lane offsets (elements)
    const int rdOff  = ln * RSTR;                 // A-read row
    const int owOff  = (4 * q) * RSTR + 4 * ln + 2 * j;        // own write (row 4q, col pair)
    const int inOff  = (4 * q) * RSTR + 64 + 4 * ln + 2 * j;   // next-layer input write

    float cst[2][2] = {{0.f, 0.f}, {0.f, 0.f}};   // c-state [s][rr]

    // ---- x pipeline (wave 0, lanes 0..31): batch xm at row rho(xm) ----
    const int xm = lane >> 2, xe = lane & 3;
    const int xrow = 4 * (xm >> 1) + (xm & 1);
    float xA = 0.0f;
    if (wave == 0 && lane < 32)
        xA = x[(size_t)(b0 + xm) * (T_ * 4) + xe];            // x(0)
    __syncthreads();   // zero-init fully done before anyone stages (fixes race)
    if (wave == 0 && lane < 32) {
        const f16 hh = (f16)xA;
        buf[0][0][0][xrow][64 + xe] = hh;
        buf[0][0][1][xrow][64 + xe] = (f16)(xA - (float)hh);
        xA = x[(size_t)(b0 + xm) * (T_ * 4) + 4 + xe];        // x(1)
    }

    auto body = [&](int i) {
        __syncthreads();                  // the ONLY barrier per iteration
        const int t = i - l;
        if (t < 0 || t >= T_) return;
        const int p = t & 1;

        // stage x(t+1) into parity p^1; prefetch x(t+2)
        if (wave == 0 && lane < 32) {
            if (t + 1 < T_) {
                const f16 hh = (f16)xA;
                buf[0][p ^ 1][0][xrow][64 + xe] = hh;
                buf[0][p ^ 1][1][xrow][64 + xe] = (f16)(xA - (float)hh);
            }
            if (t + 2 < T_)
                xA = x[(size_t)(b0 + xm) * (T_ * 4) + (t + 2) * 4 + xe];
        }

        // ---- A fragments (hi/lo planes) ----
        const f16* rb = rdB[p] + rdOff;
        f16x8 Ah[4], Al[4];
#pragma unroll
        for (int kt = 0; kt < 4; ++kt) {
            Ah[kt] = *(const f16x8*)(rb + kt * 32 + q * 8);
            Al[kt] = *(const f16x8*)(rb + 16 * RSTR + kt * 32 + q * 8);
        }

        // ---- MFMA, acc pre-initialized to (prescaled) bias ----
        f32x4 acc[4][2];
#pragma unroll
        for (int g4 = 0; g4 < 4; ++g4)
#pragma unroll
            for (int s = 0; s < 2; ++s)
                acc[g4][s] = (f32x4){biasv[g4][s], biasv[g4][s], biasv[g4][s], biasv[g4][s]};
#pragma unroll
        for (int kt = 0; kt < 4; ++kt)
#pragma unroll
            for (int g4 = 0; g4 < 4; ++g4)
#pragma unroll
                for (int s = 0; s < 2; ++s) {
                    acc[g4][s] = __builtin_amdgcn_mfma_f32_16x16x32_f16(Ah[kt], Wf[g4][s][kt], acc[g4][s], 0, 0, 0);
                    acc[g4][s] = __builtin_amdgcn_mfma_f32_16x16x32_f16(Al[kt], Wf[g4][s][kt], acc[g4][s], 0, 0, 0);
                }

        // ---- pointwise: 4 local updates (batches 2q,2q+1 x units s=0,1) ----
        const int pn = p ^ 1;
        f16* wO = wrO[pn] + owOff;
        f16* wI = wrI[p] + inOff;
#pragma unroll
        for (int rr = 0; rr < 2; ++rr) {
            f16x2 hh2, hl2;
#pragma unroll
            for (int s = 0; s < 2; ++s) {
                const float si = rcpf(1.0f + exp2f(acc[0][s][rr]));
                const float sf = rcpf(1.0f + exp2f(acc[1][s][rr]));
                const float tg = 1.0f - 2.0f * rcpf(1.0f + exp2f(acc[2][s][rr]));
                const float so = rcpf(1.0f + exp2f(acc[3][s][rr]));
                const float c  = sf * cst[s][rr] + si * tg;
                cst[s][rr] = c;
                const float tc = 1.0f - 2.0f * rcpf(1.0f + exp2f(c * (2.0f * LOG2E)));
                const float h  = so * tc;
                const f16 hhi = (f16)h;
                hh2[s] = hhi;
                hl2[s] = (f16)(h - (float)hhi);
                if (l == 3 && t == T_ - 1) hf[2 * q + rr][(2 * j + s) * 16 + ln] = h;
            }
            *(f16x2*)(wO + rr * RSTR) = hh2;
            *(f16x2*)(wO + rr * RSTR + 16 * RSTR) = hl2;
            if (l < 3) {
                *(f16x2*)(wI + rr * RSTR) = hh2;
                *(f16x2*)(wI + rr * RSTR + 16 * RSTR) = hl2;
            }
        }
    };

#pragma unroll 1
    for (int i = 0; i < T_ + 4; i += 2) {   // covers iterations 0 .. T_+3
        body(i);
        body(i + 1);
    }

    // ---- FC on h(T-1) of layer 3 ----
    __syncthreads();
    if (tid < 8 * OUT_) {
        const int b = tid / OUT_, o = tid % OUT_;
        float a = b_fc[o];
#pragma unroll
        for (int k = 0; k < H_; ++k)
            a = fmaf(hf[b][k], W_fc[o * H_ + k], a);
        out[(b0 + b) * OUT_ + o] = a;
    }
}

extern "C" void kernel_launch(void* const* d_in, const int* in_sizes, int n_in,
                              void* d_out, int out_size, void* d_ws, size_t ws_size,
                              hipStream_t stream) {
    const float* x     = (const float*)d_in[0];
    const float* W_ih0 = (const float*)d_in[1];
    const float* W_ihr = (const float*)d_in[2];
    const float* W_hh  = (const float*)d_in[3];
    const float* b_ih  = (const float*)d_in[4];
    const float* b_hh  = (const float*)d_in[5];
    const float* W_fc  = (const float*)d_in[6];
    const float* b_fc  = (const float*)d_in[7];
    float* out = (float*)d_out;

    lstm_diet_k<<<dim3(B_ / 8), dim3(512), 0, stream>>>(
        x, W_ih0, W_ihr, W_hh, b_ih, b_hh, W_fc, b_fc, out);
}

// Round 9
// 685.868 us; speedup vs baseline: 4.4085x; 1.8489x over previous
//
#include <hip/hip_runtime.h>

// Stacked LSTM B=2048,T=512,IN=4,H=64,L=4,OUT=5 — LDS-dataflow layer pipeline.
// Grid 256 (1 block/CU), block 512 (8 waves; wave-pair (2l,2l+1) = layer l,
// NB=8 batches). NO per-step __syncthreads: R6/R8 showed the block barrier
// phase-locks all 8 waves (wall ~5900 cyc/iter, busy ~2600). Instead each
// wave loops its own t=0..511 and synchronizes via LDS progress flags
// (doneP[2l+j] = steps completed), acquire/release at workgroup scope:
//   before step t: partner >= t (own-h halves + WAR on parity p^1)
//                  layer l-1 >= t+1 (input h(t) staged into my INB)
//                  layer l+1 >= t-1 (WAR: they finished reading parity p)
// The 1-step layer skew EMERGES from the deps; SIMD-sharing waves desync so
// MFMA of one overlaps the trans chain of the other.
// Precision: single-plane f16 weights AND single-plane f16 activations
// (lo-plane dropped: 32 MFMAs/step, 4 A-reads; predicted absmax ~1e-3 vs
// 2.5e-3 threshold — revert to hi/lo acts if breached).
// Weights prescaled by -log2e (i,f,o) / +2log2e (g) -> direct exp2.
// Row-spread staging rho(b)=4*(b>>1)+(b&1): every lane owns its 4 h-updates
// locally (no shfl). phi(u)=4*(u&15)+(u>>4) K-permutation -> f16x2 h writes.

#define B_    2048
#define T_    512
#define H_    64
#define OUT_  5
#define RSTR  136              // f16/row = 272 B: 16B-aligned, even read banking
#define LOG2E 1.44269504088896340736f

typedef _Float16 f16;
typedef __attribute__((ext_vector_type(8))) _Float16 f16x8;
typedef __attribute__((ext_vector_type(2))) _Float16 f16x2;
typedef __attribute__((ext_vector_type(4))) float f32x4;

__device__ __forceinline__ float rcpf(float v) { return __builtin_amdgcn_rcpf(v); }
__device__ __forceinline__ float ex2(float v)  { return __builtin_amdgcn_exp2f(v); }

__global__ __launch_bounds__(512, 2) void lstm_flow_k(
    const float* __restrict__ x,      // [B,T,4]
    const float* __restrict__ W_ih0,  // [256,4]
    const float* __restrict__ W_ihr,  // [3,256,64]
    const float* __restrict__ W_hh,   // [4,256,64]
    const float* __restrict__ b_ih,   // [4,256]
    const float* __restrict__ b_hh,   // [4,256]
    const float* __restrict__ W_fc,   // [5,64]
    const float* __restrict__ b_fc,   // [5]
    float* __restrict__ out)          // [B,5]
{
    const int tid  = threadIdx.x;
    const int wave = tid >> 6;
    const int l    = wave >> 1;       // layer 0..3
    const int j    = wave & 1;        // half of the layer's units
    const int lane = tid & 63;
    const int q    = lane >> 4;
    const int ln   = lane & 15;
    const int b0   = blockIdx.x * 8;

    // [layer][parity][row][col]: cols 0..63 own h (phi), 64..127 input. 34.8 KB.
    __shared__ f16 buf[4][2][16][RSTR];
    __shared__ int flg[8];            // doneP per (l,j)
    __shared__ float hf[8][H_ + 1];   // FC staging

    for (int k = tid; k < (int)(sizeof(buf) / 4); k += 512) ((unsigned*)buf)[k] = 0u;
    if (tid < 8) flg[tid] = 0;

    // ---- weights -> f16 B-frags in registers/AGPRs, K phi-permuted, prescaled ----
    const float* Whh = W_hh + (size_t)l * 256 * 64;
    const float* Wih = (l == 0) ? W_ih0 : (W_ihr + (size_t)(l - 1) * 256 * 64);
    const float scg[4] = {-LOG2E, -LOG2E, 2.0f * LOG2E, -LOG2E};

    f16x8 Wf[4][2][4];                // [gate][s][kt]
    float biasv[4][2];
#pragma unroll
    for (int g4 = 0; g4 < 4; ++g4)
#pragma unroll
        for (int s = 0; s < 2; ++s) {
            const int u = (2 * j + s) * 16 + ln;
            const int n = g4 * 64 + u;
            biasv[g4][s] = (b_ih[l * 256 + n] + b_hh[l * 256 + n]) * scg[g4];
#pragma unroll
            for (int kt = 0; kt < 4; ++kt) {
                f16x8 f;
#pragma unroll
                for (int jj = 0; jj < 8; ++jj) {
                    const int kap = kt * 32 + q * 8 + jj;
                    float wv;
                    if (kap < 64) {
                        const int k = ((kap & 3) << 4) | (kap >> 2);   // phi^-1
                        wv = Whh[n * 64 + k];
                    } else {
                        const int kk = kap - 64;
                        if (l == 0) wv = (kk < 4) ? Wih[n * 4 + kk] : 0.0f;
                        else { const int k = ((kk & 3) << 4) | (kk >> 2); wv = Wih[n * 64 + k]; }
                    }
                    f[jj] = (f16)(wv * scg[g4]);
                }
                Wf[g4][s][kt] = f;
            }
        }

    // ---- flag-watch lane assignment (poll all conditions in ONE ds_read) ----
    int fIdx = 0, fOff = 0;
    bool fUse = false;
    if (lane == 0)               { fIdx = 2 * l + (j ^ 1); fOff = 0;  fUse = true; }
    else if (lane == 1 && l > 0) { fIdx = 2 * l - 2;       fOff = 1;  fUse = true; }
    else if (lane == 2 && l > 0) { fIdx = 2 * l - 1;       fOff = 1;  fUse = true; }
    else if (lane == 3 && l < 3) { fIdx = 2 * l + 2;       fOff = -1; fUse = true; }
    else if (lane == 4 && l < 3) { fIdx = 2 * l + 3;       fOff = -1; fUse = true; }

    // parity-indexed base pointers / per-lane offsets
    f16* ownB[2] = {&buf[l][0][0][0], &buf[l][1][0][0]};
    const int l1 = (l < 3) ? l + 1 : 3;
    f16* inB[2]  = {&buf[l1][0][0][0], &buf[l1][1][0][0]};
    const int rdOff = ln * RSTR;
    const int owOff = 4 * q * RSTR + 4 * ln + 2 * j;
    const int inOff = 4 * q * RSTR + 64 + 4 * ln + 2 * j;

    // ---- x pipeline (wave (0,0), lanes 0..31) ----
    const int xm = lane >> 2, xe = lane & 3;
    const int xrow = 4 * (xm >> 1) + (xm & 1);
    const bool xldr = (wave == 0 && lane < 32);
    float xA = 0.0f;

    __syncthreads();                 // zero-init visible to all
    if (xldr) {
        const float x0 = x[(size_t)(b0 + xm) * (T_ * 4) + xe];
        buf[0][0][xrow][64 + xe] = (f16)x0;                       // x(0), parity 0
        xA = x[(size_t)(b0 + xm) * (T_ * 4) + 4 + xe];            // x(1)
    }
    __syncthreads();                 // x(0) staged before anyone runs

    float cst[2][2] = {{0.f, 0.f}, {0.f, 0.f}};

    auto body = [&](int t, int p) {
        // ---- acquire wait (lane-parallel poll; guard turns deadlock into
        // wrong-answer instead of timeout) ----
        unsigned guard = 0;
        for (;;) {
            int v = 0x7fffffff;
            if (fUse) v = __hip_atomic_load(&flg[fIdx], __ATOMIC_ACQUIRE,
                                            __HIP_MEMORY_SCOPE_WORKGROUP);
            if (__all(v >= t + fOff)) break;
            if (++guard > 8) __builtin_amdgcn_s_sleep(1);
            if (guard > (1u << 16)) break;
        }

        // ---- A fragments + MFMA (single f16 plane) ----
        const f16* rb = ownB[p] + rdOff;
        f16x8 A[4];
#pragma unroll
        for (int kt = 0; kt < 4; ++kt)
            A[kt] = *(const f16x8*)(rb + kt * 32 + q * 8);

        f32x4 acc[4][2];
#pragma unroll
        for (int g4 = 0; g4 < 4; ++g4)
#pragma unroll
            for (int s = 0; s < 2; ++s)
                acc[g4][s] = (f32x4){biasv[g4][s], biasv[g4][s], biasv[g4][s], biasv[g4][s]};
#pragma unroll
        for (int kt = 0; kt < 4; ++kt)
#pragma unroll
            for (int g4 = 0; g4 < 4; ++g4)
#pragma unroll
                for (int s = 0; s < 2; ++s)
                    acc[g4][s] = __builtin_amdgcn_mfma_f32_16x16x32_f16(
                        A[kt], Wf[g4][s][kt], acc[g4][s], 0, 0, 0);

        // ---- x stage for t+1 (wave (0,0)); overlaps pointwise ----
        if (xldr) {
            if (t + 1 < T_) buf[0][p ^ 1][xrow][64 + xe] = (f16)xA;
            if (t + 2 < T_) xA = x[(size_t)(b0 + xm) * (T_ * 4) + (t + 2) * 4 + xe];
        }

        // ---- pointwise: 4 local updates (batches 2q+rr, units s=0,1) ----
        f16* wO = ownB[p ^ 1] + owOff;
        f16* wI = inB[p] + inOff;
#pragma unroll
        for (int rr = 0; rr < 2; ++rr) {
            f16x2 h2;
#pragma unroll
            for (int s = 0; s < 2; ++s) {
                const float si = rcpf(1.0f + ex2(acc[0][s][rr]));
                const float sf = rcpf(1.0f + ex2(acc[1][s][rr]));
                const float tg = 1.0f - 2.0f * rcpf(1.0f + ex2(acc[2][s][rr]));
                const float so = rcpf(1.0f + ex2(acc[3][s][rr]));
                const float c  = sf * cst[s][rr] + si * tg;
                cst[s][rr] = c;
                const float tc = 1.0f - 2.0f * rcpf(1.0f + ex2(c * (2.0f * LOG2E)));
                const float h  = so * tc;
                h2[s] = (f16)h;
                if (l == 3 && t == T_ - 1) hf[2 * q + rr][(2 * j + s) * 16 + ln] = h;
            }
            *(f16x2*)(wO + rr * RSTR) = h2;                 // own recurrence (parity p^1)
            if (l < 3) *(f16x2*)(wI + rr * RSTR) = h2;      // next layer input (parity p)
        }

        // ---- release: all this wave's LDS stores drained, then publish ----
        if (lane == 0)
            __hip_atomic_store(&flg[2 * l + j], t + 1, __ATOMIC_RELEASE,
                               __HIP_MEMORY_SCOPE_WORKGROUP);
    };

#pragma unroll 1
    for (int t = 0; t < T_; t += 2) {   // parity folded to constants
        body(t, 0);
        body(t + 1, 1);
    }

    // ---- FC on h(T-1) of layer 3 ----
    __syncthreads();
    if (tid < 8 * OUT_) {
        const int b = tid / OUT_, o = tid % OUT_;
        float a = b_fc[o];
#pragma unroll
        for (int k = 0; k < H_; ++k)
            a = fmaf(hf[b][k], W_fc[o * H_ + k], a);
        out[(b0 + b) * OUT_ + o] = a;
    }
}

extern "C" void kernel_launch(void* const* d_in, const int* in_sizes, int n_in,
                              void* d_out, int out_size, void* d_ws, size_t ws_size,
                              hipStream_t stream) {
    const float* x     = (const float*)d_in[0];
    const float* W_ih0 = (const float*)d_in[1];
    const float* W_ihr = (const float*)d_in[2];
    const float* W_hh  = (const float*)d_in[3];
    const float* b_ih  = (const float*)d_in[4];
    const float* b_hh  = (const float*)d_in[5];
    const float* W_fc  = (const float*)d_in[6];
    const float* b_fc  = (const float*)d_in[7];
    float* out = (float*)d_out;

    lstm_flow_k<<<dim3(B_ / 8), dim3(512), 0, stream>>>(
        x, W_ih0, W_ihr, W_hh, b_ih, b_hh, W_fc, b_fc, out);
}

// Round 10
// 610.494 us; speedup vs baseline: 4.9528x; 1.1235x over previous
//
#include <hip/hip_runtime.h>

// Stacked LSTM B=2048,T=512,IN=4,H=64,L=4,OUT=5 — 16-wave LDS-dataflow pipeline.
// Grid 256 (1 block/CU), block 1024 = 16 waves; waves 4l..4l+3 = layer l, NB=8
// batches/block. R9 (2 waves/layer, 8 waves) hit 686us with wall ~3216 cyc/step
// vs ~1400 issue: only 2 waves/SIMD -> serial chain half-exposed. Here each
// SIMD hosts 4 waves (one per layer, phase-staggered) for 4-way chain overlap.
// Per wave: 4 N-tiles (gate g, own 16 units) x 4 K-tiles = 16 MFMAs/step
// (block total unchanged), 2 h-updates/lane (20 trans vs R9's 40).
// Sync: NO __syncthreads in the T-loop; LDS progress flags flg[wave]=steps
// done, acquire/release workgroup scope. Wave (l,jj) step t waits:
//   3 partners >= t, 4 waves of l-1 >= t+1, 4 waves of l+1 >= t-1 (WAR).
// (Safety proof as R9; partner count generalized.)
// Math: single-plane f16 weights+activations (validated R9: absmax 4.9e-4),
// prescaled -log2e (i,f,o) / +2log2e (g) -> direct exp2. Zero-C MFMA: first
// MFMA uses persistent zero quad as C (no acc-init movs); bias added in
// pointwise. Row-spread rho(b)=4*(b>>1)+(b&1): lane owns rows 4q+{0,1} ->
// batches 2q+rr locally. phi(u)=4*(u&15)+(u>>4): unit u of wave jj ->
// col 4*ln+jj. __launch_bounds__(1024,4) keeps VGPR<=128 so the whole
// 16-wave workgroup is resident (HW guarantee).

#define B_    2048
#define T_    512
#define H_    64
#define OUT_  5
#define RSTR  136              // f16/row = 272 B (16B-aligned)
#define LOG2E 1.44269504088896340736f

typedef _Float16 f16;
typedef __attribute__((ext_vector_type(8))) _Float16 f16x8;
typedef __attribute__((ext_vector_type(4))) float f32x4;

__device__ __forceinline__ float rcpf(float v) { return __builtin_amdgcn_rcpf(v); }
__device__ __forceinline__ float ex2(float v)  { return __builtin_amdgcn_exp2f(v); }

__global__ __launch_bounds__(1024, 4) void lstm_flow16_k(
    const float* __restrict__ x,      // [B,T,4]
    const float* __restrict__ W_ih0,  // [256,4]
    const float* __restrict__ W_ihr,  // [3,256,64]
    const float* __restrict__ W_hh,   // [4,256,64]
    const float* __restrict__ b_ih,   // [4,256]
    const float* __restrict__ b_hh,   // [4,256]
    const float* __restrict__ W_fc,   // [5,64]
    const float* __restrict__ b_fc,   // [5]
    float* __restrict__ out)          // [B,5]
{
    const int tid  = threadIdx.x;
    const int wave = tid >> 6;        // 0..15
    const int l    = wave >> 2;       // layer 0..3
    const int jj   = wave & 3;        // quarter of the layer's units
    const int lane = tid & 63;
    const int q    = lane >> 4;
    const int ln   = lane & 15;
    const int u    = jj * 16 + ln;    // owned hidden unit
    const int b0   = blockIdx.x * 8;

    // [layer][parity][row][col]: cols 0..63 own h (phi), 64..127 input. 34.8 KB.
    __shared__ f16 buf[4][2][16][RSTR];
    __shared__ int flg[16];
    __shared__ float hf[8][H_ + 1];   // FC staging

    for (int k = tid; k < (int)(sizeof(buf) / 4); k += 1024) ((unsigned*)buf)[k] = 0u;
    if (tid < 16) flg[tid] = 0;

    // ---- weights -> f16 B-frags (4 gates x 4 K-tiles = 64 VGPRs), prescaled ----
    const float* Whh = W_hh + (size_t)l * 256 * 64;
    const float* Wih = (l == 0) ? W_ih0 : (W_ihr + (size_t)(l - 1) * 256 * 64);
    const float scg[4] = {-LOG2E, -LOG2E, 2.0f * LOG2E, -LOG2E};

    f16x8 Wf[4][4];                   // [gate][kt]
    float biasv[4];
#pragma unroll
    for (int g4 = 0; g4 < 4; ++g4) {
        const int n = g4 * 64 + u;
        biasv[g4] = (b_ih[l * 256 + n] + b_hh[l * 256 + n]) * scg[g4];
#pragma unroll
        for (int kt = 0; kt < 4; ++kt) {
            f16x8 f;
#pragma unroll
            for (int e = 0; e < 8; ++e) {
                const int kap = kt * 32 + q * 8 + e;
                float wv;
                if (kap < 64) {
                    const int k = ((kap & 3) << 4) | (kap >> 2);   // phi^-1
                    wv = Whh[n * 64 + k];
                } else {
                    const int kk = kap - 64;
                    if (l == 0) wv = (kk < 4) ? Wih[n * 4 + kk] : 0.0f;
                    else { const int k = ((kk & 3) << 4) | (kk >> 2); wv = Wih[n * 64 + k]; }
                }
                f[e] = (f16)(wv * scg[g4]);
            }
            Wf[g4][kt] = f;
        }
    }

    // ---- flag-watch lane assignment (one flag per lane, one __all) ----
    int fIdx = 0, fOff = 0;
    bool fUse = false;
    if (lane < 3)                            { fIdx = 4 * l + ((jj + 1 + lane) & 3); fOff = 0;  fUse = true; }
    else if (lane >= 3 && lane < 7 && l > 0) { fIdx = 4 * (l - 1) + (lane - 3);      fOff = 1;  fUse = true; }
    else if (lane >= 7 && lane < 11 && l < 3){ fIdx = 4 * (l + 1) + (lane - 7);      fOff = -1; fUse = true; }

    // parity-indexed pointers / per-lane offsets
    f16* ownB[2] = {&buf[l][0][0][0], &buf[l][1][0][0]};
    const int l1 = (l < 3) ? l + 1 : 3;
    f16* inB[2]  = {&buf[l1][0][0][0], &buf[l1][1][0][0]};
    const int rdOff = ln * RSTR;
    const int owOff = 4 * q * RSTR + 4 * ln + jj;         // own h (rows 4q+rr)
    const int inOff = 4 * q * RSTR + 64 + 4 * ln + jj;    // next layer's input

    // ---- x pipeline (wave 0, lanes 0..31) ----
    const int xm = lane >> 2, xe = lane & 3;
    const int xrow = 4 * (xm >> 1) + (xm & 1);
    const bool xldr = (wave == 0 && lane < 32);
    float xA = 0.0f;

    __syncthreads();                 // zero-init visible
    if (xldr) {
        const float x0 = x[(size_t)(b0 + xm) * (T_ * 4) + xe];
        buf[0][0][xrow][64 + xe] = (f16)x0;                   // x(0), parity 0
        xA = x[(size_t)(b0 + xm) * (T_ * 4) + 4 + xe];        // x(1)
    }
    __syncthreads();                 // x(0) staged before anyone runs

    const f32x4 Z0 = {0.f, 0.f, 0.f, 0.f};   // persistent zero C-operand
    float cst[2] = {0.f, 0.f};               // c-state (batches 2q+rr)

    auto body = [&](int t, int p) {
        // ---- acquire (guard: deadlock -> wrong answer, not timeout) ----
        unsigned guard = 0;
        for (;;) {
            int v = 0x7fffffff;
            if (fUse) v = __hip_atomic_load(&flg[fIdx], __ATOMIC_ACQUIRE,
                                            __HIP_MEMORY_SCOPE_WORKGROUP);
            if (__all(v >= t + fOff)) break;
            if (++guard > 8) __builtin_amdgcn_s_sleep(1);
            if (guard > (1u << 16)) break;
        }

        // ---- A fragments + MFMA (zero-C first, bias later) ----
        const f16* rb = ownB[p] + rdOff;
        f16x8 A[4];
#pragma unroll
        for (int kt = 0; kt < 4; ++kt)
            A[kt] = *(const f16x8*)(rb + kt * 32 + q * 8);

        f32x4 acc[4];
#pragma unroll
        for (int g4 = 0; g4 < 4; ++g4)
            acc[g4] = __builtin_amdgcn_mfma_f32_16x16x32_f16(A[0], Wf[g4][0], Z0, 0, 0, 0);
#pragma unroll
        for (int kt = 1; kt < 4; ++kt)
#pragma unroll
            for (int g4 = 0; g4 < 4; ++g4)
                acc[g4] = __builtin_amdgcn_mfma_f32_16x16x32_f16(A[kt], Wf[g4][kt], acc[g4], 0, 0, 0);

        // ---- x stage for t+1 (wave 0); overlaps pointwise ----
        if (xldr) {
            if (t + 1 < T_) buf[0][p ^ 1][xrow][64 + xe] = (f16)xA;
            if (t + 2 < T_) xA = x[(size_t)(b0 + xm) * (T_ * 4) + (t + 2) * 4 + xe];
        }

        // ---- pointwise: 2 updates (batches 2q+rr, unit u) ----
        f16* wO = ownB[p ^ 1] + owOff;
        f16* wI = inB[p] + inOff;
#pragma unroll
        for (int rr = 0; rr < 2; ++rr) {
            const float si = rcpf(1.0f + ex2(acc[0][rr] + biasv[0]));
            const float sf = rcpf(1.0f + ex2(acc[1][rr] + biasv[1]));
            const float tg = 1.0f - 2.0f * rcpf(1.0f + ex2(acc[2][rr] + biasv[2]));
            const float so = rcpf(1.0f + ex2(acc[3][rr] + biasv[3]));
            const float c  = sf * cst[rr] + si * tg;
            cst[rr] = c;
            const float tc = 1.0f - 2.0f * rcpf(1.0f + ex2(c * (2.0f * LOG2E)));
            const float h  = so * tc;
            wO[rr * RSTR] = (f16)h;                     // own recurrence (parity p^1)
            if (l < 3) wI[rr * RSTR] = (f16)h;          // next layer input (parity p)
            if (l == 3 && t == T_ - 1) hf[2 * q + rr][u] = h;
        }

        // ---- release (RELEASE store drains this wave's LDS writes first) ----
        if (lane == 0)
            __hip_atomic_store(&flg[wave], t + 1, __ATOMIC_RELEASE,
                               __HIP_MEMORY_SCOPE_WORKGROUP);
    };

#pragma unroll 1
    for (int t = 0; t < T_; t += 2) {   // parity folded to constants
        body(t, 0);
        body(t + 1, 1);
    }

    // ---- FC on h(T-1) of layer 3 ----
    __syncthreads();
    if (tid < 8 * OUT_) {
        const int b = tid / OUT_, o = tid % OUT_;
        float a = b_fc[o];
#pragma unroll
        for (int k = 0; k < H_; ++k)
            a = fmaf(hf[b][k], W_fc[o * H_ + k], a);
        out[(b0 + b) * OUT_ + o] = a;
    }
}

extern "C" void kernel_launch(void* const* d_in, const int* in_sizes, int n_in,
                              void* d_out, int out_size, void* d_ws, size_t ws_size,
                              hipStream_t stream) {
    const float* x     = (const float*)d_in[0];
    const float* W_ih0 = (const float*)d_in[1];
    const float* W_ihr = (const float*)d_in[2];
    const float* W_hh  = (const float*)d_in[3];
    const float* b_ih  = (const float*)d_in[4];
    const float* b_hh  = (const float*)d_in[5];
    const float* W_fc  = (const float*)d_in[6];
    const float* b_fc  = (const float*)d_in[7];
    float* out = (float*)d_out;

    lstm_flow16_k<<<dim3(B_ / 8), dim3(1024), 0, stream>>>(
        x, W_ih0, W_ihr, W_hh, b_ih, b_hh, W_fc, b_fc, out);
}

// Round 11
// 599.887 us; speedup vs baseline: 5.0404x; 1.0177x over previous
//
#include <hip/hip_runtime.h>

// Stacked LSTM B=2048,T=512,IN=4,H=64,L=4,OUT=5 — 16-wave dataflow, DEPTH-4 ring.
// Grid 256 (1 block/CU), block 1024 = 16 waves; waves 4l..4l+3 = layer l, NB=8.
// R10 (depth-2) hit 610us: wall 2860 cyc/step vs ~1300 issue — layers were
// rate-locked (prev>=t+1, next>=t-1 bind EVERY step) and blocked waves
// spin-polled, stealing VALU issue. Here the h-buffer is a 4-slot ring:
// step t reads slot t%4, writes own-h(t) to slot (t+1)%4 and next layer's
// input to slot t%4. WAR relaxes to next>=t-3 -> layers drift up to 3 steps,
// prev>=t+1 is satisfied in advance, polls pass first try.
// Flag deps (wave (l,jj), before step t): 3 partners >= t, 4 prev >= t+1,
// 4 next >= t-3. Own-slot WAR auto-covered by partners>=t (proof: slot
// (t+1)%4 last read at step t-3 by layer-l waves; partners>=t >= t-2).
// Math (validated R9/R10, absmax 4.9e-4): single-plane f16 weights+acts,
// prescale -log2e (i,f,o) / +2log2e (g) -> direct exp2; zero-C MFMA, bias in
// pointwise; 16 MFMA/wave/step; 2 h-updates/lane; phi(u)=4*(u&15)+(u>>4)
// K-permutation; row-spread rho(b)=4*(b>>1)+(b&1).

#define B_    2048
#define T_    512
#define H_    64
#define OUT_  5
#define RSTR  136              // f16/row = 272 B (16B-aligned)
#define LOG2E 1.44269504088896340736f

typedef _Float16 f16;
typedef __attribute__((ext_vector_type(8))) _Float16 f16x8;
typedef __attribute__((ext_vector_type(4))) float f32x4;

__device__ __forceinline__ float rcpf(float v) { return __builtin_amdgcn_rcpf(v); }
__device__ __forceinline__ float ex2(float v)  { return __builtin_amdgcn_exp2f(v); }

__global__ __launch_bounds__(1024, 4) void lstm_ring_k(
    const float* __restrict__ x,      // [B,T,4]
    const float* __restrict__ W_ih0,  // [256,4]
    const float* __restrict__ W_ihr,  // [3,256,64]
    const float* __restrict__ W_hh,   // [4,256,64]
    const float* __restrict__ b_ih,   // [4,256]
    const float* __restrict__ b_hh,   // [4,256]
    const float* __restrict__ W_fc,   // [5,64]
    const float* __restrict__ b_fc,   // [5]
    float* __restrict__ out)          // [B,5]
{
    const int tid  = threadIdx.x;
    const int wave = tid >> 6;        // 0..15
    const int l    = wave >> 2;       // layer 0..3
    const int jj   = wave & 3;        // quarter of the layer's units
    const int lane = tid & 63;
    const int q    = lane >> 4;
    const int ln   = lane & 15;
    const int u    = jj * 16 + ln;    // owned hidden unit
    const int b0   = blockIdx.x * 8;

    // [layer][slot 0..3][row][col]: cols 0..63 own h (phi), 64..127 input. 68 KB.
    __shared__ f16 buf[4][4][16][RSTR];
    __shared__ int flg[16];
    __shared__ float hf[8][H_ + 1];   // FC staging

    for (int k = tid; k < (int)(sizeof(buf) / 4); k += 1024) ((unsigned*)buf)[k] = 0u;
    if (tid < 16) flg[tid] = 0;

    // ---- weights -> f16 B-frags (4 gates x 4 K-tiles = 64 VGPRs), prescaled ----
    const float* Whh = W_hh + (size_t)l * 256 * 64;
    const float* Wih = (l == 0) ? W_ih0 : (W_ihr + (size_t)(l - 1) * 256 * 64);
    const float scg[4] = {-LOG2E, -LOG2E, 2.0f * LOG2E, -LOG2E};

    f16x8 Wf[4][4];                   // [gate][kt]
    float biasv[4];
#pragma unroll
    for (int g4 = 0; g4 < 4; ++g4) {
        const int n = g4 * 64 + u;
        biasv[g4] = (b_ih[l * 256 + n] + b_hh[l * 256 + n]) * scg[g4];
#pragma unroll
        for (int kt = 0; kt < 4; ++kt) {
            f16x8 f;
#pragma unroll
            for (int e = 0; e < 8; ++e) {
                const int kap = kt * 32 + q * 8 + e;
                float wv;
                if (kap < 64) {
                    const int k = ((kap & 3) << 4) | (kap >> 2);   // phi^-1
                    wv = Whh[n * 64 + k];
                } else {
                    const int kk = kap - 64;
                    if (l == 0) wv = (kk < 4) ? Wih[n * 4 + kk] : 0.0f;
                    else { const int k = ((kk & 3) << 4) | (kk >> 2); wv = Wih[n * 64 + k]; }
                }
                f[e] = (f16)(wv * scg[g4]);
            }
            Wf[g4][kt] = f;
        }
    }

    // ---- flag-watch lane assignment (one flag per lane, one __all) ----
    int fIdx = 0, fOff = 0;
    bool fUse = false;
    if (lane < 3)                             { fIdx = 4 * l + ((jj + 1 + lane) & 3); fOff = 0;  fUse = true; }
    else if (lane >= 3 && lane < 7 && l > 0)  { fIdx = 4 * (l - 1) + (lane - 3);      fOff = 1;  fUse = true; }
    else if (lane >= 7 && lane < 11 && l < 3) { fIdx = 4 * (l + 1) + (lane - 7);      fOff = -3; fUse = true; }

    // per-lane offsets (elements)
    const int l1 = (l < 3) ? l + 1 : 3;
    const int rdOff = ln * RSTR;
    const int owOff = 4 * q * RSTR + 4 * ln + jj;         // own h (rows 4q+rr)
    const int inOff = 4 * q * RSTR + 64 + 4 * ln + jj;    // next layer's input

    // ---- x pipeline (wave 0, lanes 0..31) ----
    const int xm = lane >> 2, xe = lane & 3;
    const int xrow = 4 * (xm >> 1) + (xm & 1);
    const bool xldr = (wave == 0 && lane < 32);
    float xA = 0.0f;

    __syncthreads();                 // zero-init visible
    if (xldr) {
        const float x0 = x[(size_t)(b0 + xm) * (T_ * 4) + xe];
        buf[0][0][xrow][64 + xe] = (f16)x0;                   // x(0), slot 0
        xA = x[(size_t)(b0 + xm) * (T_ * 4) + 4 + xe];        // x(1)
    }
    __syncthreads();                 // x(0) staged before anyone runs

    const f32x4 Z0 = {0.f, 0.f, 0.f, 0.f};   // persistent zero C-operand
    float cst[2] = {0.f, 0.f};               // c-state (batches 2q+rr)

    auto body = [&](int t, int sl) {
        const int sn = (sl + 1) & 3;
        // ---- acquire (guard: deadlock -> wrong answer, not timeout) ----
        unsigned guard = 0;
        for (;;) {
            int v = 0x7fffffff;
            if (fUse) v = __hip_atomic_load(&flg[fIdx], __ATOMIC_ACQUIRE,
                                            __HIP_MEMORY_SCOPE_WORKGROUP);
            if (__all(v >= t + fOff)) break;
            if (++guard > 2) __builtin_amdgcn_s_sleep(1);
            if (guard > (1u << 16)) break;
        }

        // ---- A fragments + MFMA (zero-C first, bias later) ----
        const f16* rb = &buf[l][sl][0][0] + rdOff;
        f16x8 A[4];
#pragma unroll
        for (int kt = 0; kt < 4; ++kt)
            A[kt] = *(const f16x8*)(rb + kt * 32 + q * 8);

        f32x4 acc[4];
#pragma unroll
        for (int g4 = 0; g4 < 4; ++g4)
            acc[g4] = __builtin_amdgcn_mfma_f32_16x16x32_f16(A[0], Wf[g4][0], Z0, 0, 0, 0);
#pragma unroll
        for (int kt = 1; kt < 4; ++kt)
#pragma unroll
            for (int g4 = 0; g4 < 4; ++g4)
                acc[g4] = __builtin_amdgcn_mfma_f32_16x16x32_f16(A[kt], Wf[g4][kt], acc[g4], 0, 0, 0);

        // ---- x stage for t+1 (wave 0) -> slot sn; overlaps pointwise ----
        if (xldr) {
            if (t + 1 < T_) buf[0][sn][xrow][64 + xe] = (f16)xA;
            if (t + 2 < T_) xA = x[(size_t)(b0 + xm) * (T_ * 4) + (t + 2) * 4 + xe];
        }

        // ---- pointwise: 2 updates (batches 2q+rr, unit u) ----
        f16* wO = &buf[l][sn][0][0] + owOff;       // own h(t) -> slot t+1
        f16* wI = &buf[l1][sl][0][0] + inOff;      // next layer input(t) -> slot t
#pragma unroll
        for (int rr = 0; rr < 2; ++rr) {
            const float si = rcpf(1.0f + ex2(acc[0][rr] + biasv[0]));
            const float sf = rcpf(1.0f + ex2(acc[1][rr] + biasv[1]));
            const float tg = 1.0f - 2.0f * rcpf(1.0f + ex2(acc[2][rr] + biasv[2]));
            const float so = rcpf(1.0f + ex2(acc[3][rr] + biasv[3]));
            const float c  = sf * cst[rr] + si * tg;
            cst[rr] = c;
            const float tc = 1.0f - 2.0f * rcpf(1.0f + ex2(c * (2.0f * LOG2E)));
            const float h  = so * tc;
            wO[rr * RSTR] = (f16)h;                     // own recurrence
            if (l < 3) wI[rr * RSTR] = (f16)h;          // next layer input
            if (l == 3 && t == T_ - 1) hf[2 * q + rr][u] = h;
        }

        // ---- release (drains this wave's LDS writes first) ----
        if (lane == 0)
            __hip_atomic_store(&flg[wave], t + 1, __ATOMIC_RELEASE,
                               __HIP_MEMORY_SCOPE_WORKGROUP);
    };

#pragma unroll 1
    for (int t = 0; t < T_; t += 4) {   // slot folded to constants
        body(t, 0);
        body(t + 1, 1);
        body(t + 2, 2);
        body(t + 3, 3);
    }

    // ---- FC on h(T-1) of layer 3 ----
    __syncthreads();
    if (tid < 8 * OUT_) {
        const int b = tid / OUT_, o = tid % OUT_;
        float a = b_fc[o];
#pragma unroll
        for (int k = 0; k < H_; ++k)
            a = fmaf(hf[b][k], W_fc[o * H_ + k], a);
        out[(b0 + b) * OUT_ + o] = a;
    }
}

extern "C" void kernel_launch(void* const* d_in, const int* in_sizes, int n_in,
                              void* d_out, int out_size, void* d_ws, size_t ws_size,
                              hipStream_t stream) {
    const float* x     = (const float*)d_in[0];
    const float* W_ih0 = (const float*)d_in[1];
    const float* W_ihr = (const float*)d_in[2];
    const float* W_hh  = (const float*)d_in[3];
    const float* b_ih  = (const float*)d_in[4];
    const float* b_hh  = (const float*)d_in[5];
    const float* W_fc  = (const float*)d_in[6];
    const float* b_fc  = (const float*)d_in[7];
    float* out = (float*)d_out;

    lstm_ring_k<<<dim3(B_ / 8), dim3(1024), 0, stream>>>(
        x, W_ih0, W_ihr, W_hh, b_ih, b_hh, W_fc, b_fc, out);
}